// Round 5
// baseline (2616.141 us; speedup 1.0000x reference)
//
#include <hip/hip_runtime.h>
#include <hip/hip_bf16.h>

typedef _Float16 f16;
typedef __attribute__((ext_vector_type(8))) _Float16 f16x8;
typedef __attribute__((ext_vector_type(4))) _Float16 f16x4;
typedef __attribute__((ext_vector_type(4))) float f32x4;

#define GLOAD_LDS16(gp, lp) \
  __builtin_amdgcn_global_load_lds((const __attribute__((address_space(1))) void*)(gp), \
                                   (__attribute__((address_space(3))) void*)(lp), 16, 0, 0)

// ---------------- all weight casts in one dispatch ----------------
__global__ __launch_bounds__(256) void cast_all_k(const float* __restrict__ cw,
                                                  const float* __restrict__ wqk,
                                                  const float* __restrict__ wv,
                                                  const float* __restrict__ wt,
                                                  f16* __restrict__ Wc, f16* __restrict__ Wq,
                                                  f16* __restrict__ Wv_, f16* __restrict__ Wt_){
  int y = blockIdx.y;
  const float* in; f16* out; int n;
  if (y == 0){ in = cw;  out = Wc;  n = 6 * 65536; }
  else if (y == 1){ in = wqk; out = Wq;  n = 8 * 65536; }
  else if (y == 2){ in = wv;  out = Wv_; n = 8 * 65536; }
  else { in = wt;  out = Wt_; n = 8 * 65536; }
  int i = (blockIdx.x * 256 + threadIdx.x) * 4;
  if (i < n){
    f32x4 v = *(const f32x4*)(in + i);
    f16x4 o;
    o[0] = (f16)v[0]; o[1] = (f16)v[1]; o[2] = (f16)v[2]; o[3] = (f16)v[3];
    *(f16x4*)(out + i) = o;
  }
}

// ---------------- f32 [b][c][n] -> fp16 [b][n][c] ----------------
__global__ __launch_bounds__(256) void transpose_f16_k(const float* __restrict__ X,
                                                       f16* __restrict__ XT){
  __shared__ float tile[64][65];
  int b = blockIdx.z, c0 = blockIdx.y * 64, n0 = blockIdx.x * 64;
  int t = threadIdx.x, nl = t & 63, cr = t >> 6;
  long base = (long)b * 65536;
#pragma unroll
  for (int i = 0; i < 16; i++){
    int cl = cr + 4 * i;
    tile[cl][nl] = X[base + (c0 + cl) * 256 + (n0 + nl)];
  }
  __syncthreads();
  int cl2 = t & 63, nr2 = t >> 6;
#pragma unroll
  for (int i = 0; i < 16; i++){
    int nl2 = nr2 + 4 * i;
    XT[base + (n0 + nl2) * 256 + (c0 + cl2)] = (f16)tile[cl2][nl2];
  }
}

// ---------------- GEMM fp16: C[m][n] = sum_k A[m][k] * BT[n][k], 256^3 per batch ----------------
// global_load_lds (width 16) staging into linear LDS [128][64] (m97 structure).
// STATS: per-block channel partial (sum, sumsq) -> Ps/Pq [256][512] (deterministic).
#define EPI_EF32      0
#define EPI_BIAS_F32  1
#define EPI_T16       2
#define EPI_BIAS_F16  3
#define EPI_PV_DT     4

template<int EPI, bool STATS>
__global__ __launch_bounds__(256) void gemm_f16(
    const f16* __restrict__ A, long sA,
    const f16* __restrict__ Bt,
    float* __restrict__ Cf, long sC,
    f16* __restrict__ Oh,
    const float* __restrict__ bias,
    const float* __restrict__ U,
    float* __restrict__ Ps, float* __restrict__ Pq)
{
  __shared__ f16 As[128][64];
  __shared__ f16 Bs[128][64];
  int b  = blockIdx.z;
  int m0 = blockIdx.y * 128, n0 = blockIdx.x * 128;
  const f16* Ab = A  + (long)b * sA;
  const f16* Bb = Bt + (long)b * 65536;
  int t = threadIdx.x;
  int lane = t & 63, wid = t >> 6;
  int wm = (wid >> 1) * 64, wn = (wid & 1) * 64;
  f32x4 acc[4][4] = {};

  int lr = lane >> 3;          // row-in-chunk 0..7
  int kc = (lane & 7) * 8;     // col 0..56 (f16), 16B units

  for (int kt = 0; kt < 4; kt++){
    int k0 = kt * 64;
    if (kt) __syncthreads();   // previous tile's ds_reads drained at this barrier
#pragma unroll
    for (int i = 0; i < 4; i++){
      int chunk = wid * 4 + i;           // wave-uniform
      int r = chunk * 8 + lr;
      GLOAD_LDS16(Ab + (m0 + r) * 256 + k0 + kc, &As[chunk * 8][0]);
      GLOAD_LDS16(Bb + (n0 + r) * 256 + k0 + kc, &Bs[chunk * 8][0]);
    }
    __syncthreads();           // vmcnt(0) drain before barrier -> LDS ready
#pragma unroll
    for (int ks = 0; ks < 2; ks++){
      f16x8 af[4], bfr[4];
      int ko = ks * 32 + (lane >> 4) * 8;
#pragma unroll
      for (int mi = 0; mi < 4; mi++)
        af[mi] = *(const f16x8*)(&As[wm + mi * 16 + (lane & 15)][ko]);
#pragma unroll
      for (int ni = 0; ni < 4; ni++)
        bfr[ni] = *(const f16x8*)(&Bs[wn + ni * 16 + (lane & 15)][ko]);
#pragma unroll
      for (int mi = 0; mi < 4; mi++)
#pragma unroll
        for (int ni = 0; ni < 4; ni++)
          acc[mi][ni] = __builtin_amdgcn_mfma_f32_16x16x32_f16(af[mi], bfr[ni], acc[mi][ni], 0, 0, 0);
    }
  }

  float* ssum = (float*)&As[0][0];   // [128][2] after MFMA done
  float* ssq  = ssum + 256;
  if constexpr (STATS) __syncthreads();

  int mg0 = m0 + wm + ((lane >> 4) << 2);
  int ng0 = n0 + wn + (lane & 15);
#pragma unroll
  for (int mi = 0; mi < 4; mi++){
    float sr[4] = {0.f, 0.f, 0.f, 0.f}, qr[4] = {0.f, 0.f, 0.f, 0.f};
#pragma unroll
    for (int ni = 0; ni < 4; ni++){
      int mg = mg0 + mi * 16;
      int ng = ng0 + ni * 16;
      f32x4 v = acc[mi][ni];
      if constexpr (EPI == EPI_EF32){
        float* Cb = Cf + (long)b * sC;
#pragma unroll
        for (int r = 0; r < 4; r++){
          float vv = v[r];
          Cb[(mg + r) * 256 + ng] = vv;
          if constexpr (STATS){ sr[r] += vv; qr[r] += vv * vv; }
        }
      } else if constexpr (EPI == EPI_BIAS_F32){
        float* Cb = Cf + (long)b * sC;
#pragma unroll
        for (int r = 0; r < 4; r++){
          float vv = v[r] + bias[mg + r];
          Cb[(mg + r) * 256 + ng] = vv;
          if constexpr (STATS){ sr[r] += vv; qr[r] += vv * vv; }
        }
      } else if constexpr (EPI == EPI_T16){
        f16* Ohb = Oh + (long)b * 65536;
        f16x4 p;
#pragma unroll
        for (int r = 0; r < 4; r++) p[r] = (f16)v[r];
        *(f16x4*)(&Ohb[ng * 256 + mg]) = p;
      } else if constexpr (EPI == EPI_BIAS_F16){
        f16* Ohb = Oh + (long)b * 65536;
#pragma unroll
        for (int r = 0; r < 4; r++) Ohb[(mg + r) * 256 + ng] = (f16)(v[r] + bias[mg + r]);
      } else if constexpr (EPI == EPI_PV_DT){
        const float* Ub = U + (long)b * 65536;
        f16* Ohb = Oh + (long)b * 65536;
        f16x4 p;
#pragma unroll
        for (int r = 0; r < 4; r++) p[r] = (f16)(Ub[(mg + r) * 256 + ng] - v[r]);
        *(f16x4*)(&Ohb[ng * 256 + mg]) = p;
      }
    }
    if constexpr (STATS){
#pragma unroll
      for (int r = 0; r < 4; r++){
        float s = sr[r], q = qr[r];
        s += __shfl_xor(s, 1); q += __shfl_xor(q, 1);
        s += __shfl_xor(s, 2); q += __shfl_xor(q, 2);
        s += __shfl_xor(s, 4); q += __shfl_xor(q, 4);
        s += __shfl_xor(s, 8); q += __shfl_xor(q, 8);
        if ((lane & 15) == 0){
          int ch = wm + mi * 16 + (lane >> 4) * 4 + r;
          int half = wid & 1;
          ssum[ch * 2 + half] = s;
          ssq [ch * 2 + half] = q;
        }
      }
    }
  }
  if constexpr (STATS){
    __syncthreads();
    if (t < 128){
      int c = m0 + t;
      float S = ssum[t * 2] + ssum[t * 2 + 1];
      float Q = ssq [t * 2] + ssq [t * 2 + 1];
      long off = (long)c * 512 + b * 2 + blockIdx.x;
      Ps[off] = S; Pq[off] = Q;
    }
  }
}

// ---------------- finalize BN stats from per-block partials ----------------
__global__ __launch_bounds__(256) void bn_reduce_k(const float* __restrict__ Ps,
                                                   const float* __restrict__ Pq,
                                                   float* __restrict__ mean, float* __restrict__ rstd){
  int c = blockIdx.x, t = threadIdx.x;
  float s = Ps[c * 512 + t] + Ps[c * 512 + t + 256];
  float q = Pq[c * 512 + t] + Pq[c * 512 + t + 256];
  for (int off = 32; off > 0; off >>= 1){ s += __shfl_down(s, off); q += __shfl_down(q, off); }
  __shared__ float ss[4], qq[4];
  int lane = t & 63, w = t >> 6;
  if (lane == 0){ ss[w] = s; qq[w] = q; }
  __syncthreads();
  if (t == 0){
    float S = ss[0] + ss[1] + ss[2] + ss[3];
    float Q = qq[0] + qq[1] + qq[2] + qq[3];
    float m = S * (1.f / 65536.f);
    float var = Q * (1.f / 65536.f) - m * m;
    mean[c] = m;
    rstd[c] = rsqrtf(var + 1e-5f);
  }
}

// ---------------- per softmax-row stats: mx, rs = 1/sum(exp); E batch stride 262144 ----------------
__global__ __launch_bounds__(256) void rowstat_k(const float* __restrict__ E,
                                                 float* __restrict__ mx, float* __restrict__ rs){
  int rid = blockIdx.x * 4 + (threadIdx.x >> 6);
  int lane = threadIdx.x & 63;
  int b = rid >> 8, n = rid & 255;
  const float* row = E + (long)b * 262144 + n * 256;
  float v[4];
  float m = -1e30f;
#pragma unroll
  for (int i = 0; i < 4; i++){ v[i] = row[lane + 64 * i]; m = fmaxf(m, v[i]); }
  for (int off = 32; off > 0; off >>= 1) m = fmaxf(m, __shfl_xor(m, off));
  float s = 0.f;
#pragma unroll
  for (int i = 0; i < 4; i++) s += __expf(v[i] - m);
  for (int off = 32; off > 0; off >>= 1) s += __shfl_xor(s, off);
  if (lane == 0){ mx[rid] = m; rs[rid] = 1.f / s; }
}

// ---------------- attnT[b][m][n] = exp(E[b][m][n]-mx[bn])*rs[bn] / (eps + rowsum), fp16 ----------------
// uses E symmetry -> row-major pass; E batch stride 262144
__global__ __launch_bounds__(256) void renorm_k(const float* __restrict__ E,
                                                const float* __restrict__ mx,
                                                const float* __restrict__ rs,
                                                f16* __restrict__ AT){
  int rid = blockIdx.x * 4 + (threadIdx.x >> 6);   // b*256 + m
  int lane = threadIdx.x & 63;
  int b = rid >> 8, m = rid & 255;
  const float* row = E + (long)b * 262144 + m * 256;
  const float* mxb = mx + (b << 8);
  const float* rsb = rs + (b << 8);
  float tv[4];
  float cs = 0.f;
#pragma unroll
  for (int i = 0; i < 4; i++){
    int n = lane + 64 * i;
    tv[i] = __expf(row[n] - mxb[n]) * rsb[n];
    cs += tv[i];
  }
  for (int off = 32; off > 0; off >>= 1) cs += __shfl_xor(cs, off);
  float inv = 1.f / (1e-9f + cs);
  f16* orow = AT + (long)rid * 256;
#pragma unroll
  for (int i = 0; i < 4; i++) orow[lane + 64 * i] = (f16)(tv[i] * inv);
}

// ---------------- BN apply + relu (+2x residual) + layout writes ----------------
template<bool RESID, bool WN32, bool WT32, bool WN16, bool WT16, bool WDOUT>
__global__ __launch_bounds__(256) void bn_apply_k(
    const float* __restrict__ Y, const float* __restrict__ U,
    const float* __restrict__ mean, const float* __restrict__ rstd,
    const float* __restrict__ gamma, const float* __restrict__ beta,
    float* __restrict__ on32, float* __restrict__ ot32,
    f16* __restrict__ on16, f16* __restrict__ ot16,
    float* __restrict__ odout)
{
  __shared__ float tile[64][65];
  int b = blockIdx.z, c0 = blockIdx.y * 64, n0 = blockIdx.x * 64;
  int t = threadIdx.x, nl = t & 63, cr = t >> 6;
  long base = (long)b * 65536;
#pragma unroll
  for (int i = 0; i < 16; i++){
    int cl = cr + 4 * i;
    int c = c0 + cl, n = n0 + nl;
    long idx = base + c * 256 + n;
    float y = Y[idx];
    float v = fmaxf((y - mean[c]) * rstd[c] * gamma[c] + beta[c], 0.f);
    if constexpr (RESID) v += 2.f * U[idx];
    if constexpr (WN32) on32[idx] = v;
    if constexpr (WN16) on16[idx] = (f16)v;
    if constexpr (WDOUT) odout[(long)b * 262144 + c * 256 + n] = v;
    if constexpr (WT32 || WT16) tile[cl][nl] = v;
  }
  if constexpr (WT32 || WT16){
    __syncthreads();
    int cl2 = t & 63, nr2 = t >> 6;
#pragma unroll
    for (int i = 0; i < 16; i++){
      int nl2 = nr2 + 4 * i;
      long tidx = base + (n0 + nl2) * 256 + (c0 + cl2);
      float v = tile[cl2][nl2];
      if constexpr (WT32) ot32[tidx] = v;
      if constexpr (WT16) ot16[tidx] = (f16)v;
    }
  }
}

extern "C" void kernel_launch(void* const* d_in, const int* in_sizes, int n_in,
                              void* d_out, int out_size, void* d_ws, size_t ws_size,
                              hipStream_t stream)
{
  (void)in_sizes; (void)n_in; (void)out_size; (void)ws_size;

  const float* x0  = (const float*)d_in[0];
  const float* cw  = (const float*)d_in[1];
  const float* bng = (const float*)d_in[2];
  const float* bnb = (const float*)d_in[3];
  const float* wqk = (const float*)d_in[4];
  const float* wv  = (const float*)d_in[5];
  const float* bv  = (const float*)d_in[6];
  const float* wt  = (const float*)d_in[7];
  const float* bt  = (const float*)d_in[8];
  const float* sag = (const float*)d_in[9];
  const float* sab = (const float*)d_in[10];

  const long T = 16777216; // elements per [B,C,N] tensor
  float* Un0 = (float*)d_ws;       // u (f32, normal) even slots
  float* Un1 = Un0 + T;            // u (f32, normal) odd slots
  float* F1  = Un1 + T;            // pre-BN GEMM output f32
  f16*  Ht   = (f16*)(F1 + T);     // uT fp16 (GEMM BT operand)
  f16*  XK   = Ht + T;             // xkT, then xv
  f16*  ATb  = XK + T;             // attnT fp16
  f16*  DT   = ATb + T;            // dT fp16
  f16*  Wc   = DT + T;
  f16*  Wq   = Wc + 6 * 65536;
  f16*  Wv_  = Wq + 8 * 65536;
  f16*  Wt_  = Wv_ + 8 * 65536;
  float* mx  = (float*)(Wt_ + 8 * 65536);
  float* rs  = mx + 65536;
  float* mn  = rs + 65536;
  float* rsd = mn + 256;
  float* Ps  = rsd + 256;          // [256][512] channel partial sums
  float* Pq  = Ps + 131072;        // [256][512] channel partial sumsq
  float* E   = (float*)d_out + 196608; // d_out region 3 as energy scratch (batch stride 262144!)

  dim3 thr(256);
  dim3 gg(2, 2, 256);
  dim3 tile(4, 4, 256);

  cast_all_k<<<dim3(512, 4), thr, 0, stream>>>(cw, wqk, wv, wt, Wc, Wq, Wv_, Wt_);
  transpose_f16_k<<<tile, thr, 0, stream>>>(x0, Ht);

  // conv0: x = relu(bn(W x)) -> only xT fp16 needed
  gemm_f16<EPI_EF32, true><<<gg, thr, 0, stream>>>(Wc, 0, Ht, F1, 65536, nullptr, nullptr, nullptr, Ps, Pq);
  bn_reduce_k<<<256, thr, 0, stream>>>(Ps, Pq, mn, rsd);
  bn_apply_k<false, false, false, false, true, false><<<tile, thr, 0, stream>>>(
      F1, nullptr, mn, rsd, bng, bnb, nullptr, nullptr, nullptr, Ht, nullptr);
  // conv1: -> Un0 (residual) + Ht
  gemm_f16<EPI_EF32, true><<<gg, thr, 0, stream>>>(Wc + 65536, 0, Ht, F1, 65536, nullptr, nullptr, nullptr, Ps, Pq);
  bn_reduce_k<<<256, thr, 0, stream>>>(Ps, Pq, mn, rsd);
  bn_apply_k<false, true, false, false, true, false><<<tile, thr, 0, stream>>>(
      F1, nullptr, mn, rsd, bng + 256, bnb + 256, Un0, nullptr, nullptr, Ht, nullptr);

  for (int blk = 0; blk < 4; blk++){
    for (int s = 0; s < 2; s++){
      int li = 2 * blk + s;
      float* u = (s == 0) ? Un0 : Un1;
      // xkT = (wqk u)^T fp16
      gemm_f16<EPI_T16, false><<<gg, thr, 0, stream>>>(Wq + li * 65536, 0, Ht, nullptr, 0, XK, nullptr, nullptr, nullptr, nullptr);
      // E[n][m] = <xk_n, xk_m> f32 (symmetric), batch stride 262144
      gemm_f16<EPI_EF32, false><<<gg, thr, 0, stream>>>(XK, 65536, XK, E, 262144, nullptr, nullptr, nullptr, nullptr, nullptr);
      rowstat_k<<<dim3(16384), thr, 0, stream>>>(E, mx, rs);
      renorm_k<<<dim3(16384), thr, 0, stream>>>(E, mx, rs, ATb);
      // xv = wv u + bv, fp16 normal (reuse XK)
      gemm_f16<EPI_BIAS_F16, false><<<gg, thr, 0, stream>>>(Wv_ + li * 65536, 0, Ht, nullptr, 0, XK, bv + li * 256, nullptr, nullptr, nullptr);
      // dT = (u - xv attn')^T fp16
      gemm_f16<EPI_PV_DT, false><<<gg, thr, 0, stream>>>(XK, 65536, ATb, nullptr, 0, DT, nullptr, u, nullptr, nullptr);
      // y = wt d + bt -> F1 f32 (+ fused BN partials)
      gemm_f16<EPI_BIAS_F32, true><<<gg, thr, 0, stream>>>(Wt_ + li * 65536, 0, DT, F1, 65536, nullptr, bt + li * 256, nullptr, Ps, Pq);
      bn_reduce_k<<<256, thr, 0, stream>>>(Ps, Pq, mn, rsd);
      if (s == 0){
        // x1 = 2u + relu(bn(y)); Ht <- x1 (next uT), Un1 <- x1^T (next u)
        bn_apply_k<true, false, true, true, false, false><<<tile, thr, 0, stream>>>(
            F1, u, mn, rsd, sag + li * 256, sab + li * 256, nullptr, Un1, Ht, nullptr, nullptr);
      } else {
        // x11pre = 2u + relu(bn(y)); Ht <- (x11pre)^T (conv BT operand)
        bn_apply_k<true, false, false, false, true, false><<<tile, thr, 0, stream>>>(
            F1, u, mn, rsd, sag + li * 256, sab + li * 256, nullptr, nullptr, nullptr, Ht, nullptr);
      }
    }
    // block conv + bn + relu -> d_out region blk, Un0 (next u), Ht (next uT)
    gemm_f16<EPI_EF32, true><<<gg, thr, 0, stream>>>(Wc + (blk + 2) * 65536, 0, Ht, F1, 65536, nullptr, nullptr, nullptr, Ps, Pq);
    bn_reduce_k<<<256, thr, 0, stream>>>(Ps, Pq, mn, rsd);
    bn_apply_k<false, true, false, false, true, true><<<tile, thr, 0, stream>>>(
        F1, nullptr, mn, rsd, bng + (blk + 2) * 256, bnb + (blk + 2) * 256,
        Un0, nullptr, nullptr, Ht, (float*)d_out + blk * 65536);
  }
}

// Round 6
// 2370.571 us; speedup vs baseline: 1.1036x; 1.1036x over previous
//
#include <hip/hip_runtime.h>
#include <hip/hip_bf16.h>

typedef _Float16 f16;
typedef __attribute__((ext_vector_type(8))) _Float16 f16x8;
typedef __attribute__((ext_vector_type(4))) _Float16 f16x4;
typedef __attribute__((ext_vector_type(4))) float f32x4;

#define GLOAD_LDS16(gp, lp) \
  __builtin_amdgcn_global_load_lds((const __attribute__((address_space(1))) void*)(gp), \
                                   (__attribute__((address_space(3))) void*)(lp), 16, 0, 0)

// ---------------- all weight casts in one dispatch ----------------
__global__ __launch_bounds__(256) void cast_all_k(const float* __restrict__ cw,
                                                  const float* __restrict__ wqk,
                                                  const float* __restrict__ wv,
                                                  const float* __restrict__ wt,
                                                  f16* __restrict__ Wc, f16* __restrict__ Wq,
                                                  f16* __restrict__ Wv_, f16* __restrict__ Wt_){
  int y = blockIdx.y;
  const float* in; f16* out; int n;
  if (y == 0){ in = cw;  out = Wc;  n = 6 * 65536; }
  else if (y == 1){ in = wqk; out = Wq;  n = 8 * 65536; }
  else if (y == 2){ in = wv;  out = Wv_; n = 8 * 65536; }
  else { in = wt;  out = Wt_; n = 8 * 65536; }
  int i = (blockIdx.x * 256 + threadIdx.x) * 4;
  if (i < n){
    f32x4 v = *(const f32x4*)(in + i);
    f16x4 o;
    o[0] = (f16)v[0]; o[1] = (f16)v[1]; o[2] = (f16)v[2]; o[3] = (f16)v[3];
    *(f16x4*)(out + i) = o;
  }
}

// ---------------- f32 [b][c][n] -> fp16 [b][n][c] ----------------
__global__ __launch_bounds__(256) void transpose_f16_k(const float* __restrict__ X,
                                                       f16* __restrict__ XT){
  __shared__ float tile[64][65];
  int b = blockIdx.z, c0 = blockIdx.y * 64, n0 = blockIdx.x * 64;
  int t = threadIdx.x, nl = t & 63, cr = t >> 6;
  long base = (long)b * 65536;
#pragma unroll
  for (int i = 0; i < 16; i++){
    int cl = cr + 4 * i;
    tile[cl][nl] = X[base + (c0 + cl) * 256 + (n0 + nl)];
  }
  __syncthreads();
  int cl2 = t & 63, nr2 = t >> 6;
#pragma unroll
  for (int i = 0; i < 16; i++){
    int nl2 = nr2 + 4 * i;
    XT[base + (n0 + nl2) * 256 + (c0 + cl2)] = (f16)tile[cl2][nl2];
  }
}

// ---------------- GEMM fp16: C[m][n] = sum_k A[m][k] * BT[n][k], 256^3 per batch ----------------
// global_load_lds (width 16) into linear LDS [128][64]; XOR-swizzle applied on the
// GLOBAL source (inverse) and the ds_read side: LDS[row][e] = glob[row][e ^ ((row&7)<<3)].
// STATS: per-block channel partial (sum, sumsq) -> Ps/Pq [256][512] (deterministic).
#define EPI_EF32      0
#define EPI_BIAS_F32  1
#define EPI_T16       2
#define EPI_BIAS_F16  3
#define EPI_PV_DT     4

template<int EPI, bool STATS>
__global__ __launch_bounds__(256) void gemm_f16(
    const f16* __restrict__ A, long sA,
    const f16* __restrict__ Bt,
    float* __restrict__ Cf, long sC,
    f16* __restrict__ Oh,
    const float* __restrict__ bias,
    const float* __restrict__ U,
    float* __restrict__ Ps, float* __restrict__ Pq)
{
  __shared__ f16 As[128][64];
  __shared__ f16 Bs[128][64];
  int b  = blockIdx.z;
  int m0 = blockIdx.y * 128, n0 = blockIdx.x * 128;
  const f16* Ab = A  + (long)b * sA;
  const f16* Bb = Bt + (long)b * 65536;
  int t = threadIdx.x;
  int lane = t & 63, wid = t >> 6;
  int wm = (wid >> 1) * 64, wn = (wid & 1) * 64;
  f32x4 acc[4][4] = {};

  int lr = lane >> 3;                         // row-in-chunk 0..7
  int kc = ((lane & 7) ^ lr) * 8;             // inverse-swizzled global column

  for (int kt = 0; kt < 4; kt++){
    int k0 = kt * 64;
    if (kt) __syncthreads();   // previous tile's ds_reads drained at this barrier
#pragma unroll
    for (int i = 0; i < 4; i++){
      int chunk = wid * 4 + i;           // wave-uniform
      int r = chunk * 8 + lr;
      GLOAD_LDS16(Ab + (m0 + r) * 256 + k0 + kc, &As[chunk * 8][0]);
      GLOAD_LDS16(Bb + (n0 + r) * 256 + k0 + kc, &Bs[chunk * 8][0]);
    }
    __syncthreads();           // vmcnt(0) drain before barrier -> LDS ready
#pragma unroll
    for (int ks = 0; ks < 2; ks++){
      f16x8 af[4], bfr[4];
      int ko = ks * 32 + (lane >> 4) * 8;
#pragma unroll
      for (int mi = 0; mi < 4; mi++){
        int rA = wm + mi * 16 + (lane & 15);
        af[mi] = *(const f16x8*)(&As[rA][ko ^ ((rA & 7) << 3)]);
      }
#pragma unroll
      for (int ni = 0; ni < 4; ni++){
        int rB = wn + ni * 16 + (lane & 15);
        bfr[ni] = *(const f16x8*)(&Bs[rB][ko ^ ((rB & 7) << 3)]);
      }
#pragma unroll
      for (int mi = 0; mi < 4; mi++)
#pragma unroll
        for (int ni = 0; ni < 4; ni++)
          acc[mi][ni] = __builtin_amdgcn_mfma_f32_16x16x32_f16(af[mi], bfr[ni], acc[mi][ni], 0, 0, 0);
    }
  }

  float* ssum = (float*)&As[0][0];   // [128][2] after MFMA done
  float* ssq  = ssum + 256;
  if constexpr (STATS) __syncthreads();

  int mg0 = m0 + wm + ((lane >> 4) << 2);
  int ng0 = n0 + wn + (lane & 15);
#pragma unroll
  for (int mi = 0; mi < 4; mi++){
    float sr[4] = {0.f, 0.f, 0.f, 0.f}, qr[4] = {0.f, 0.f, 0.f, 0.f};
#pragma unroll
    for (int ni = 0; ni < 4; ni++){
      int mg = mg0 + mi * 16;
      int ng = ng0 + ni * 16;
      f32x4 v = acc[mi][ni];
      if constexpr (EPI == EPI_EF32){
        float* Cb = Cf + (long)b * sC;
#pragma unroll
        for (int r = 0; r < 4; r++){
          float vv = v[r];
          Cb[(mg + r) * 256 + ng] = vv;
          if constexpr (STATS){ sr[r] += vv; qr[r] += vv * vv; }
        }
      } else if constexpr (EPI == EPI_BIAS_F32){
        float* Cb = Cf + (long)b * sC;
#pragma unroll
        for (int r = 0; r < 4; r++){
          float vv = v[r] + bias[mg + r];
          Cb[(mg + r) * 256 + ng] = vv;
          if constexpr (STATS){ sr[r] += vv; qr[r] += vv * vv; }
        }
      } else if constexpr (EPI == EPI_T16){
        f16* Ohb = Oh + (long)b * 65536;
        f16x4 p;
#pragma unroll
        for (int r = 0; r < 4; r++) p[r] = (f16)v[r];
        *(f16x4*)(&Ohb[ng * 256 + mg]) = p;
      } else if constexpr (EPI == EPI_BIAS_F16){
        f16* Ohb = Oh + (long)b * 65536;
#pragma unroll
        for (int r = 0; r < 4; r++) Ohb[(mg + r) * 256 + ng] = (f16)(v[r] + bias[mg + r]);
      } else if constexpr (EPI == EPI_PV_DT){
        const float* Ub = U + (long)b * 65536;
        f16* Ohb = Oh + (long)b * 65536;
        f16x4 p;
#pragma unroll
        for (int r = 0; r < 4; r++) p[r] = (f16)(Ub[(mg + r) * 256 + ng] - v[r]);
        *(f16x4*)(&Ohb[ng * 256 + mg]) = p;
      }
    }
    if constexpr (STATS){
#pragma unroll
      for (int r = 0; r < 4; r++){
        float s = sr[r], q = qr[r];
        s += __shfl_xor(s, 1); q += __shfl_xor(q, 1);
        s += __shfl_xor(s, 2); q += __shfl_xor(q, 2);
        s += __shfl_xor(s, 4); q += __shfl_xor(q, 4);
        s += __shfl_xor(s, 8); q += __shfl_xor(q, 8);
        if ((lane & 15) == 0){
          int ch = wm + mi * 16 + (lane >> 4) * 4 + r;
          int half = wid & 1;
          ssum[ch * 2 + half] = s;
          ssq [ch * 2 + half] = q;
        }
      }
    }
  }
  if constexpr (STATS){
    __syncthreads();
    if (t < 128){
      int c = m0 + t;
      float S = ssum[t * 2] + ssum[t * 2 + 1];
      float Q = ssq [t * 2] + ssq [t * 2 + 1];
      long off = (long)c * 512 + b * 2 + blockIdx.x;
      Ps[off] = S; Pq[off] = Q;
    }
  }
}

// ---------------- finalize BN stats from per-block partials ----------------
__global__ __launch_bounds__(256) void bn_reduce_k(const float* __restrict__ Ps,
                                                   const float* __restrict__ Pq,
                                                   float* __restrict__ mean, float* __restrict__ rstd){
  int c = blockIdx.x, t = threadIdx.x;
  float s = Ps[c * 512 + t] + Ps[c * 512 + t + 256];
  float q = Pq[c * 512 + t] + Pq[c * 512 + t + 256];
  for (int off = 32; off > 0; off >>= 1){ s += __shfl_down(s, off); q += __shfl_down(q, off); }
  __shared__ float ss[4], qq[4];
  int lane = t & 63, w = t >> 6;
  if (lane == 0){ ss[w] = s; qq[w] = q; }
  __syncthreads();
  if (t == 0){
    float S = ss[0] + ss[1] + ss[2] + ss[3];
    float Q = qq[0] + qq[1] + qq[2] + qq[3];
    float m = S * (1.f / 65536.f);
    float var = Q * (1.f / 65536.f) - m * m;
    mean[c] = m;
    rstd[c] = rsqrtf(var + 1e-5f);
  }
}

// ---------------- per softmax-row stats: mx, rs = 1/sum(exp); E batch stride 262144 ----------------
__global__ __launch_bounds__(256) void rowstat_k(const float* __restrict__ E,
                                                 float* __restrict__ mx, float* __restrict__ rs){
  int rid = blockIdx.x * 4 + (threadIdx.x >> 6);
  int lane = threadIdx.x & 63;
  int b = rid >> 8, n = rid & 255;
  const float* row = E + (long)b * 262144 + n * 256;
  float v[4];
  float m = -1e30f;
#pragma unroll
  for (int i = 0; i < 4; i++){ v[i] = row[lane + 64 * i]; m = fmaxf(m, v[i]); }
  for (int off = 32; off > 0; off >>= 1) m = fmaxf(m, __shfl_xor(m, off));
  float s = 0.f;
#pragma unroll
  for (int i = 0; i < 4; i++) s += __expf(v[i] - m);
  for (int off = 32; off > 0; off >>= 1) s += __shfl_xor(s, off);
  if (lane == 0){ mx[rid] = m; rs[rid] = 1.f / s; }
}

// ---------------- attnT[b][m][n] = exp(E[b][m][n]-mx[bn])*rs[bn] / (eps + rowsum), fp16 ----------------
// uses E symmetry -> row-major pass; E batch stride 262144
__global__ __launch_bounds__(256) void renorm_k(const float* __restrict__ E,
                                                const float* __restrict__ mx,
                                                const float* __restrict__ rs,
                                                f16* __restrict__ AT){
  int rid = blockIdx.x * 4 + (threadIdx.x >> 6);   // b*256 + m
  int lane = threadIdx.x & 63;
  int b = rid >> 8, m = rid & 255;
  const float* row = E + (long)b * 262144 + m * 256;
  const float* mxb = mx + (b << 8);
  const float* rsb = rs + (b << 8);
  float tv[4];
  float cs = 0.f;
#pragma unroll
  for (int i = 0; i < 4; i++){
    int n = lane + 64 * i;
    tv[i] = __expf(row[n] - mxb[n]) * rsb[n];
    cs += tv[i];
  }
  for (int off = 32; off > 0; off >>= 1) cs += __shfl_xor(cs, off);
  float inv = 1.f / (1e-9f + cs);
  f16* orow = AT + (long)rid * 256;
#pragma unroll
  for (int i = 0; i < 4; i++) orow[lane + 64 * i] = (f16)(tv[i] * inv);
}

// ---------------- BN apply + relu (+2x residual) + layout writes ----------------
template<bool RESID, bool WN32, bool WT32, bool WN16, bool WT16, bool WDOUT>
__global__ __launch_bounds__(256) void bn_apply_k(
    const float* __restrict__ Y, const float* __restrict__ U,
    const float* __restrict__ mean, const float* __restrict__ rstd,
    const float* __restrict__ gamma, const float* __restrict__ beta,
    float* __restrict__ on32, float* __restrict__ ot32,
    f16* __restrict__ on16, f16* __restrict__ ot16,
    float* __restrict__ odout)
{
  __shared__ float tile[64][65];
  int b = blockIdx.z, c0 = blockIdx.y * 64, n0 = blockIdx.x * 64;
  int t = threadIdx.x, nl = t & 63, cr = t >> 6;
  long base = (long)b * 65536;
#pragma unroll
  for (int i = 0; i < 16; i++){
    int cl = cr + 4 * i;
    int c = c0 + cl, n = n0 + nl;
    long idx = base + c * 256 + n;
    float y = Y[idx];
    float v = fmaxf((y - mean[c]) * rstd[c] * gamma[c] + beta[c], 0.f);
    if constexpr (RESID) v += 2.f * U[idx];
    if constexpr (WN32) on32[idx] = v;
    if constexpr (WN16) on16[idx] = (f16)v;
    if constexpr (WDOUT) odout[(long)b * 262144 + c * 256 + n] = v;
    if constexpr (WT32 || WT16) tile[cl][nl] = v;
  }
  if constexpr (WT32 || WT16){
    __syncthreads();
    int cl2 = t & 63, nr2 = t >> 6;
#pragma unroll
    for (int i = 0; i < 16; i++){
      int nl2 = nr2 + 4 * i;
      long tidx = base + (n0 + nl2) * 256 + (c0 + cl2);
      float v = tile[cl2][nl2];
      if constexpr (WT32) ot32[tidx] = v;
      if constexpr (WT16) ot16[tidx] = (f16)v;
    }
  }
}

extern "C" void kernel_launch(void* const* d_in, const int* in_sizes, int n_in,
                              void* d_out, int out_size, void* d_ws, size_t ws_size,
                              hipStream_t stream)
{
  (void)in_sizes; (void)n_in; (void)out_size; (void)ws_size;

  const float* x0  = (const float*)d_in[0];
  const float* cw  = (const float*)d_in[1];
  const float* bng = (const float*)d_in[2];
  const float* bnb = (const float*)d_in[3];
  const float* wqk = (const float*)d_in[4];
  const float* wv  = (const float*)d_in[5];
  const float* bv  = (const float*)d_in[6];
  const float* wt  = (const float*)d_in[7];
  const float* bt  = (const float*)d_in[8];
  const float* sag = (const float*)d_in[9];
  const float* sab = (const float*)d_in[10];

  const long T = 16777216; // elements per [B,C,N] tensor
  float* Un0 = (float*)d_ws;       // u (f32, normal) even slots
  float* Un1 = Un0 + T;            // u (f32, normal) odd slots
  float* F1  = Un1 + T;            // pre-BN GEMM output f32
  f16*  Ht   = (f16*)(F1 + T);     // uT fp16 (GEMM BT operand)
  f16*  XK   = Ht + T;             // xkT, then xv
  f16*  ATb  = XK + T;             // attnT fp16
  f16*  DT   = ATb + T;            // dT fp16
  f16*  Wc   = DT + T;
  f16*  Wq   = Wc + 6 * 65536;
  f16*  Wv_  = Wq + 8 * 65536;
  f16*  Wt_  = Wv_ + 8 * 65536;
  float* mx  = (float*)(Wt_ + 8 * 65536);
  float* rs  = mx + 65536;
  float* mn  = rs + 65536;
  float* rsd = mn + 256;
  float* Ps  = rsd + 256;          // [256][512] channel partial sums
  float* Pq  = Ps + 131072;        // [256][512] channel partial sumsq
  float* E   = (float*)d_out + 196608; // d_out region 3 as energy scratch (batch stride 262144!)

  dim3 thr(256);
  dim3 gg(2, 2, 256);
  dim3 tile(4, 4, 256);

  cast_all_k<<<dim3(512, 4), thr, 0, stream>>>(cw, wqk, wv, wt, Wc, Wq, Wv_, Wt_);
  transpose_f16_k<<<tile, thr, 0, stream>>>(x0, Ht);

  // conv0: x = relu(bn(W x)) -> only xT fp16 needed
  gemm_f16<EPI_EF32, true><<<gg, thr, 0, stream>>>(Wc, 0, Ht, F1, 65536, nullptr, nullptr, nullptr, Ps, Pq);
  bn_reduce_k<<<256, thr, 0, stream>>>(Ps, Pq, mn, rsd);
  bn_apply_k<false, false, false, false, true, false><<<tile, thr, 0, stream>>>(
      F1, nullptr, mn, rsd, bng, bnb, nullptr, nullptr, nullptr, Ht, nullptr);
  // conv1: -> Un0 (residual) + Ht
  gemm_f16<EPI_EF32, true><<<gg, thr, 0, stream>>>(Wc + 65536, 0, Ht, F1, 65536, nullptr, nullptr, nullptr, Ps, Pq);
  bn_reduce_k<<<256, thr, 0, stream>>>(Ps, Pq, mn, rsd);
  bn_apply_k<false, true, false, false, true, false><<<tile, thr, 0, stream>>>(
      F1, nullptr, mn, rsd, bng + 256, bnb + 256, Un0, nullptr, nullptr, Ht, nullptr);

  for (int blk = 0; blk < 4; blk++){
    for (int s = 0; s < 2; s++){
      int li = 2 * blk + s;
      float* u = (s == 0) ? Un0 : Un1;
      // xkT = (wqk u)^T fp16
      gemm_f16<EPI_T16, false><<<gg, thr, 0, stream>>>(Wq + li * 65536, 0, Ht, nullptr, 0, XK, nullptr, nullptr, nullptr, nullptr);
      // E[n][m] = <xk_n, xk_m> f32 (symmetric), batch stride 262144
      gemm_f16<EPI_EF32, false><<<gg, thr, 0, stream>>>(XK, 65536, XK, E, 262144, nullptr, nullptr, nullptr, nullptr, nullptr);
      rowstat_k<<<dim3(16384), thr, 0, stream>>>(E, mx, rs);
      renorm_k<<<dim3(16384), thr, 0, stream>>>(E, mx, rs, ATb);
      // xv = wv u + bv, fp16 normal (reuse XK)
      gemm_f16<EPI_BIAS_F16, false><<<gg, thr, 0, stream>>>(Wv_ + li * 65536, 0, Ht, nullptr, 0, XK, bv + li * 256, nullptr, nullptr, nullptr);
      // dT = (u - xv attn')^T fp16
      gemm_f16<EPI_PV_DT, false><<<gg, thr, 0, stream>>>(XK, 65536, ATb, nullptr, 0, DT, nullptr, u, nullptr, nullptr);
      // y = wt d + bt -> F1 f32 (+ fused BN partials)
      gemm_f16<EPI_BIAS_F32, true><<<gg, thr, 0, stream>>>(Wt_ + li * 65536, 0, DT, F1, 65536, nullptr, bt + li * 256, nullptr, Ps, Pq);
      bn_reduce_k<<<256, thr, 0, stream>>>(Ps, Pq, mn, rsd);
      if (s == 0){
        // x1 = 2u + relu(bn(y)); Ht <- x1 (next uT), Un1 <- x1^T (next u)
        bn_apply_k<true, false, true, true, false, false><<<tile, thr, 0, stream>>>(
            F1, u, mn, rsd, sag + li * 256, sab + li * 256, nullptr, Un1, Ht, nullptr, nullptr);
      } else {
        // x11pre = 2u + relu(bn(y)); Ht <- (x11pre)^T (conv BT operand)
        bn_apply_k<true, false, false, false, true, false><<<tile, thr, 0, stream>>>(
            F1, u, mn, rsd, sag + li * 256, sab + li * 256, nullptr, nullptr, nullptr, Ht, nullptr);
      }
    }
    // block conv + bn + relu -> d_out region blk, Un0 (next u), Ht (next uT)
    gemm_f16<EPI_EF32, true><<<gg, thr, 0, stream>>>(Wc + (blk + 2) * 65536, 0, Ht, F1, 65536, nullptr, nullptr, nullptr, Ps, Pq);
    bn_reduce_k<<<256, thr, 0, stream>>>(Ps, Pq, mn, rsd);
    bn_apply_k<false, true, false, false, true, true><<<tile, thr, 0, stream>>>(
        F1, nullptr, mn, rsd, bng + (blk + 2) * 256, bnb + (blk + 2) * 256,
        Un0, nullptr, nullptr, Ht, (float*)d_out + blk * 65536);
  }
}